// Round 10
// baseline (133.571 us; speedup 1.0000x reference)
//
#include <hip/hip_runtime.h>
#include <hip/hip_bf16.h>
#include <math.h>

// ScreeningAttention: B=2, T=2048, D_MODEL=768, H=12, D=64
// k_cvtW (Wq/Wk/Wv/Wo f32->bf16) -> k_proj (128x128 MFMA GEMM, A read directly
// from f32 X via reg-staging+convert, B double-buffered gload_lds; l2norm,
// V transposed) -> k_attn (balanced causal screening attn, double-buffered)
// -> k_outproj (128x128 GEMM, double-buffered).
// NOTE: v_cvt_pk_bf16_f32 inline-asm packing was a correctness bug (r4/6/7);
// bit-manip RNE is the proven path.

typedef __attribute__((ext_vector_type(8))) short short8;     // 8 bf16, MFMA A/B frag
typedef __attribute__((ext_vector_type(4))) float f32x4;      // MFMA C/D frag
typedef __attribute__((ext_vector_type(4))) unsigned int uint4v;
typedef __attribute__((ext_vector_type(2))) unsigned int uint2v;
typedef __attribute__((ext_vector_type(4))) float float4v;

#define MFMA_BF16(a, b, c) __builtin_amdgcn_mfma_f32_16x16x32_bf16((a), (b), (c), 0, 0, 0)

// round-to-nearest-even f32->bf16, bit-manip (round-3-proven).
static __device__ __forceinline__ unsigned short f2bf(float f) {
  union { float f; unsigned u; } v; v.f = f;
  unsigned r = v.u + 0x7FFFu + ((v.u >> 16) & 1u);
  return (unsigned short)(r >> 16);
}
static __device__ __forceinline__ unsigned pack2(float a, float b) {
  return (unsigned)f2bf(a) | ((unsigned)f2bf(b) << 16);
}
// async global->LDS, 16B per lane. LDS dest = wave-uniform base + lane*16.
static __device__ __forceinline__ void gload_lds16(const void* g, void* l) {
  __builtin_amdgcn_global_load_lds((const __attribute__((address_space(1))) unsigned int*)g,
                                   (__attribute__((address_space(3))) unsigned int*)l, 16, 0, 0);
}

// ---------------------------------------------------------------------------
// Kernel 0: convert Wq,Wk,Wv,Wo (4x589824) f32->bf16 contiguous.
// grid 1152x256, 8 elems/thread. (X is no longer pre-converted -- k_proj
// reads f32 X directly.)
// ---------------------------------------------------------------------------
__global__ __launch_bounds__(256) void k_cvtW(
    const float* __restrict__ s3, const float* __restrict__ s4, const float* __restrict__ s5,
    const float* __restrict__ s6, unsigned short* __restrict__ dst) {
  const size_t e = ((size_t)blockIdx.x * 256 + threadIdx.x) * 8;
  const int i = (int)(e / 589824);
  const float* src = (i == 0) ? s3 : (i == 1) ? s4 : (i == 2) ? s5 : s6;
  const size_t off = e - (size_t)i * 589824;
  const float4v f0 = *(const float4v*)(src + off);
  const float4v f1 = *(const float4v*)(src + off + 4);
  uint4v u = {pack2(f0.x, f0.y), pack2(f0.z, f0.w), pack2(f1.x, f1.y), pack2(f1.z, f1.w)};
  *(uint4v*)(dst + e) = u;
}

// ---------------------------------------------------------------------------
// Kernel 1: QKV projection + per-head l2 normalization.
// 128x128 tile, BK=64, 4 waves (2x2, 64x64 each, 4x4 frags).
// A-operand: read f32 X DIRECTLY per-wave into registers (prefetched one
// k-step ahead), converted to bf16 frags in-register (lane (l4,l15) needs
// exactly rows wm*64+m*16+l15, cols kc*32+l4*8..+8 -- contiguous 32B).
// B-operand: Wb bf16, double-buffered gload_lds with XOR chunk-swizzle
// (unchanged round-9-proven schedule: vmcnt(0) -> barrier -> prefetch -> MFMA).
// which==2 (V) writes TRANSPOSED to vtb [bh][d][t].
// grid = (32, 6, 3); block = 256. LDS 34.8 KB (B bufs @0/@16K; epilogue alias).
// ---------------------------------------------------------------------------
__global__ __launch_bounds__(256) void k_proj(
    const float* __restrict__ Xq, const float* __restrict__ Xk, const float* __restrict__ Xv,
    const unsigned short* __restrict__ Wb, unsigned short* __restrict__ qb,
    unsigned short* __restrict__ kb, unsigned short* __restrict__ vtb) {
  __shared__ alignas(16) unsigned char smem[34816];
  float* o_s = (float*)smem;                     // f32[128][68] epilogue alias
  unsigned short* vt_s = (unsigned short*)smem;  // bf16[64][136] V epilogue alias

  const int which = blockIdx.z;
  const float* X = (which == 0) ? Xq : (which == 1) ? Xk : Xv;
  const unsigned short* W = Wb + (size_t)which * 589824;

  const int mbase = blockIdx.x * 128;
  const int nb = blockIdx.y;  // 2 heads per block
  const int tid = threadIdx.x;
  const int lane = tid & 63;
  const int wv = tid >> 6;
  const int wm = wv >> 1, wn = wv & 1;
  const int l15 = lane & 15, l4 = lane >> 4;

  const int srow8 = lane >> 3;
  const int schunk = (lane & 7) ^ srow8;

  f32x4 acc[4][4];
#pragma unroll
  for (int m = 0; m < 4; ++m)
#pragma unroll
    for (int n = 0; n < 4; ++n) acc[m][n] = (f32x4){0.f, 0.f, 0.f, 0.f};

  // per-lane A source rows (fixed all k-steps)
  const float* arow[4];
#pragma unroll
  for (int m = 0; m < 4; ++m)
    arow[m] = X + (size_t)(mbase + wm * 64 + m * 16 + l15) * 768 + l4 * 8;

  // A f32 prefetch buffer: [m][kc][half] (64 VGPR)
  float4v af[4][2][2];

  // prologue: load A(ks=0) to regs; issue B(ks=0) gload into buf 0
#pragma unroll
  for (int m = 0; m < 4; ++m)
#pragma unroll
    for (int kc = 0; kc < 2; ++kc)
#pragma unroll
      for (int hf = 0; hf < 2; ++hf)
        af[m][kc][hf] = *(const float4v*)(arow[m] + kc * 32 + hf * 4);
#pragma unroll
  for (int i = 0; i < 4; ++i) {
    const int j = wv * 4 + i;
    gload_lds16(W + (size_t)(nb * 128 + j * 8 + srow8) * 768 + schunk * 8, smem + j * 1024);
  }

  for (int ks = 0; ks < 12; ++ks) {
    const int cur = (ks & 1) * 16384;
    // my A(ks) regs + B(ks) gloads done -> barrier -> everyone's B staged
    asm volatile("s_waitcnt vmcnt(0)" ::: "memory");
    __builtin_amdgcn_sched_barrier(0);
    __builtin_amdgcn_s_barrier();
    __builtin_amdgcn_sched_barrier(0);
    // convert current A f32 -> bf16 frags (frees af for next prefetch)
    short8 afr[4][2];
#pragma unroll
    for (int m = 0; m < 4; ++m)
#pragma unroll
      for (int kc = 0; kc < 2; ++kc) {
        union { uint4v u; short8 s; } cv;
        cv.u = (uint4v){pack2(af[m][kc][0].x, af[m][kc][0].y),
                        pack2(af[m][kc][0].z, af[m][kc][0].w),
                        pack2(af[m][kc][1].x, af[m][kc][1].y),
                        pack2(af[m][kc][1].z, af[m][kc][1].w)};
        afr[m][kc] = cv.s;
      }
    // prefetch ks+1: A to regs, B to the other LDS buffer
    if (ks < 11) {
      const int k0n = (ks + 1) * 64;
      const int nxt = ((ks + 1) & 1) * 16384;
#pragma unroll
      for (int m = 0; m < 4; ++m)
#pragma unroll
        for (int kc = 0; kc < 2; ++kc)
#pragma unroll
          for (int hf = 0; hf < 2; ++hf)
            af[m][kc][hf] = *(const float4v*)(arow[m] + k0n + kc * 32 + hf * 4);
#pragma unroll
      for (int i = 0; i < 4; ++i) {
        const int j = wv * 4 + i;
        gload_lds16(W + (size_t)(nb * 128 + j * 8 + srow8) * 768 + k0n + schunk * 8,
                    smem + nxt + j * 1024);
      }
      __builtin_amdgcn_sched_barrier(0);  // pin prefetch issue before compute
    }
    __builtin_amdgcn_s_setprio(1);
#pragma unroll
    for (int kc = 0; kc < 2; ++kc) {
      const int cx = (kc << 2) | l4;
      short8 br[4];
#pragma unroll
      for (int n = 0; n < 4; ++n) {
        const int r = wn * 64 + n * 16 + l15;
        br[n] = *(const short8*)(smem + cur + r * 128 + ((cx ^ (r & 7)) << 4));
      }
#pragma unroll
      for (int m = 0; m < 4; ++m)
#pragma unroll
        for (int n = 0; n < 4; ++n) acc[m][n] = MFMA_BF16(afr[m][kc], br[n], acc[m][n]);
    }
    __builtin_amdgcn_s_setprio(0);
  }

  // epilogue: per col-half pass p (head h = nb*2+p)
  const int b = mbase >> 11;
  const int tbase = mbase & 2047;
  const int row2 = tid >> 1, half = tid & 1;
  for (int p = 0; p < 2; ++p) {
    __syncthreads();
    if (wn == p) {
#pragma unroll
      for (int m = 0; m < 4; ++m)
#pragma unroll
        for (int n = 0; n < 4; ++n)
#pragma unroll
          for (int j = 0; j < 4; ++j)
            o_s[(wm * 64 + m * 16 + l4 * 4 + j) * 68 + n * 16 + l15] = acc[m][n][j];
    }
    __syncthreads();
    float v[32];
    float ss = 0.f;
#pragma unroll
    for (int c = 0; c < 8; ++c) {
      float4v f = *(const float4v*)(o_s + row2 * 68 + half * 32 + c * 4);
      v[c * 4 + 0] = f.x; v[c * 4 + 1] = f.y; v[c * 4 + 2] = f.z; v[c * 4 + 3] = f.w;
      ss += f.x * f.x + f.y * f.y + f.z * f.z + f.w * f.w;
    }
    ss += __shfl_xor(ss, 1);
    const float inv = 1.f / fmaxf(sqrtf(ss), 1e-8f);
    const int h = nb * 2 + p, bh = b * 12 + h;
    if (which < 2) {
      unsigned short* outp =
          ((which == 0) ? qb : kb) + ((size_t)bh * 2048 + tbase + row2) * 64 + half * 32;
#pragma unroll
      for (int c = 0; c < 4; ++c) {
        uint4v o = {pack2(v[c * 8 + 0] * inv, v[c * 8 + 1] * inv),
                    pack2(v[c * 8 + 2] * inv, v[c * 8 + 3] * inv),
                    pack2(v[c * 8 + 4] * inv, v[c * 8 + 5] * inv),
                    pack2(v[c * 8 + 6] * inv, v[c * 8 + 7] * inv)};
        *(uint4v*)(outp + c * 8) = o;
      }
      __syncthreads();
    } else {
      __syncthreads();  // o_s reads done; vt_s aliases o_s
#pragma unroll
      for (int c = 0; c < 32; ++c)
        vt_s[(half * 32 + c) * 136 + row2] = f2bf(v[c] * inv);
      __syncthreads();
      const int d = tid >> 2, tc = (tid & 3) * 32;
      unsigned short* dst = vtb + ((size_t)bh * 64 + d) * 2048 + tbase + tc;
#pragma unroll
      for (int c = 0; c < 4; ++c)
        *(uint4v*)(dst + c * 8) = *(const uint4v*)(vt_s + d * 136 + tc + c * 8);
      __syncthreads();
    }
  }
}

// ---------------------------------------------------------------------------
// Kernel 2: causal screening attention (ROUND-8/9 PASSING, unchanged).
// Swapped-S MFMA (reg-dim = keys), Q staged via LDS then held in registers,
// K/V^T DOUBLE-BUFFERED via global_load_lds; full vmcnt(0) drains only.
// LDS: K0 @0, K1 @8192, V0 @16384, V1 @24576, p_s @32768 (9216), Q @41984.
// block = 256 (4 waves, 2x2).
// ---------------------------------------------------------------------------
__global__ __launch_bounds__(256) void k_attn(
    const unsigned short* __restrict__ qb, const unsigned short* __restrict__ kb,
    const unsigned short* __restrict__ vtb, const float* __restrict__ s_v,
    const float* __restrict__ s_r, unsigned short* __restrict__ attn) {
  __shared__ alignas(16) unsigned char smem[50176];
  unsigned short* p_s = (unsigned short*)(smem + 32768);  // [64 q][72 key] bf16
  float* o_s = (float*)smem;                              // [64][68] f32 epilogue alias

  const int bid = blockIdx.x;
  const int ii = bid & 255, jj = bid >> 8;
  const int rank = (jj == 0) ? ii : (jj == 1) ? (511 - ii) : (512 + ii);
  const int qt = 31 - (rank / 24);  // heavy tasks at low rank
  const int bh = rank % 24;
  const int b = bh / 12, h = bh % 12;
  const int qbase = qt * 64;
  const unsigned short* Qp = qb + (size_t)bh * 2048 * 64;
  const unsigned short* Kp = kb + (size_t)bh * 2048 * 64;
  const unsigned short* VTp = vtb + (size_t)bh * 64 * 2048;

  const int tid = threadIdx.x;
  const int lane = tid & 63;
  const int wv = tid >> 6;
  const int wm = wv >> 1, wn = wv & 1;  // S: wm=keys, wn=q. PV: wm=d, wn=q.
  const int l15 = lane & 15, l4 = lane >> 4;
  const int srow8 = lane >> 3;
  const int schunk = (lane & 7) ^ srow8;

  const float w_h = expf(s_v[h]) + 1.0f;          // decay exponent, [2,256]
  const float lr_h = log2f(expf(s_r[h]) + 1.0f);  // log2 of per-head scale

  // prologue: stage Q + kt=0 K/V; FULL drain (vmcnt(0)) -- issue-order-proof.
#pragma unroll
  for (int i = 0; i < 2; ++i) {
    const int j = wv * 2 + i;
    gload_lds16(Qp + (size_t)(qbase + j * 8 + srow8) * 64 + schunk * 8, smem + 41984 + j * 1024);
  }
#pragma unroll
  for (int i = 0; i < 2; ++i) {
    const int j = wv * 2 + i;
    gload_lds16(Kp + (size_t)(j * 8 + srow8) * 64 + schunk * 8, smem + j * 1024);
    gload_lds16(VTp + (size_t)(j * 8 + srow8) * 2048 + schunk * 8, smem + 16384 + j * 1024);
  }
  asm volatile("s_waitcnt vmcnt(0)" ::: "memory");
  __builtin_amdgcn_sched_barrier(0);
  __builtin_amdgcn_s_barrier();
  __builtin_amdgcn_sched_barrier(0);

  // Q fragments (B-operand of swapped S) from LDS once
  short8 qf[2][2];
#pragma unroll
  for (int n = 0; n < 2; ++n)
#pragma unroll
    for (int kc = 0; kc < 2; ++kc) {
      const int r = wn * 32 + n * 16 + l15;
      const int cx = (kc << 2) | l4;
      qf[n][kc] = *(const short8*)(smem + 41984 + r * 128 + ((cx ^ (r & 7)) << 4));
    }

  f32x4 acc_o[2][2];  // [qi][di]
#pragma unroll
  for (int m = 0; m < 2; ++m)
#pragma unroll
    for (int n = 0; n < 2; ++n) acc_o[m][n] = (f32x4){0.f, 0.f, 0.f, 0.f};

  for (int kt = 0; kt <= qt; ++kt) {
    const int cur = (kt & 1) * 8192;
    // wait current tile's K/V (the only outstanding VMEM = prev prefetch), sync
    asm volatile("s_waitcnt vmcnt(0)" ::: "memory");
    __builtin_amdgcn_sched_barrier(0);
    __builtin_amdgcn_s_barrier();
    __builtin_amdgcn_sched_barrier(0);
    // prefetch kt+1 into the other buffer (all waves past kt-1 reads now)
    if (kt < qt) {
      const int nxt = ((kt + 1) & 1) * 8192;
      const int kb2 = (kt + 1) * 64;
#pragma unroll
      for (int i = 0; i < 2; ++i) {
        const int j = wv * 2 + i;
        gload_lds16(Kp + (size_t)(kb2 + j * 8 + srow8) * 64 + schunk * 8, smem + nxt + j * 1024);
        gload_lds16(VTp + (size_t)(j * 8 + srow8) * 2048 + kb2 + schunk * 8,
                    smem + 16384 + nxt + j * 1024);
      }
      __builtin_amdgcn_sched_barrier(0);  // pin prefetch issue before compute
    }
    // S^T = K Q^T : rows = keys, cols = q
    f32x4 s_acc[2][2];
#pragma unroll
    for (int m = 0; m < 2; ++m)
#pragma unroll
      for (int n = 0; n < 2; ++n) s_acc[m][n] = (f32x4){0.f, 0.f, 0.f, 0.f};
    __builtin_amdgcn_s_setprio(1);
#pragma unroll
    for (int kc = 0; kc < 2; ++kc) {
      const int cx = (kc << 2) | l4;
      const int r0 = wm * 32 + l15, r1 = wm * 32 + 16 + l15;
      short8 a0 = *(const short8*)(smem + cur + r0 * 128 + ((cx ^ (r0 & 7)) << 4));
      short8 a1 = *(const short8*)(smem + cur + r1 * 128 + ((cx ^ (r1 & 7)) << 4));
      s_acc[0][0] = MFMA_BF16(a0, qf[0][kc], s_acc[0][0]);
      s_acc[0][1] = MFMA_BF16(a0, qf[1][kc], s_acc[0][1]);
      s_acc[1][0] = MFMA_BF16(a1, qf[0][kc], s_acc[1][0]);
      s_acc[1][1] = MFMA_BF16(a1, qf[1][kc], s_acc[1][1]);
    }
    __builtin_amdgcn_s_setprio(0);
    // alpha = r * clamp((s+1)/2)^w ; frag reg-dim = consecutive keys -> b64 stores
    const bool diag = (kt == qt);
#pragma unroll
    for (int m = 0; m < 2; ++m)
#pragma unroll
      for (int n = 0; n < 2; ++n) {
        const int lkb = wm * 32 + m * 16 + l4 * 4;  // key base (reg dim)
        const int lq = wn * 32 + n * 16 + l15;      // q (lane dim)
        float av[4];
#pragma unroll
        for (int t = 0; t < 4; ++t) {
          const float base = __builtin_amdgcn_fmed3f(fmaf(s_acc[m][n][t], 0.5f, 0.5f), 0.f, 1.f);
          float a = __builtin_amdgcn_exp2f(fmaf(w_h, __builtin_amdgcn_logf(base), lr_h));
          if (diag && (lkb + t) > lq) a = 0.f;
          av[t] = a;
        }
        uint2v u = {pack2(av[0], av[1]), pack2(av[2], av[3])};
        *(uint2v*)(p_s + lq * 72 + lkb) = u;
      }
    // drain LDS writes of P, then sync (raw barrier: keep prefetch in flight)
    asm volatile("s_waitcnt lgkmcnt(0)" ::: "memory");
    __builtin_amdgcn_sched_barrier(0);
    __builtin_amdgcn_s_barrier();
    __builtin_amdgcn_sched_barrier(0);
    // O += P V : A = P[q][key] (padded b128 rows), B = V^T[d][key] (swizzled)
    __builtin_amdgcn_s_setprio(1);
#pragma unroll
    for (int kc = 0; kc < 2; ++kc) {
      const int cx = (kc << 2) | l4;
      const int r0 = wm * 32 + l15, r1 = wm * 32 + 16 + l15;
      short8 pa0 = *(const short8*)(p_s + (wn * 32 + l15) * 72 + kc * 32 + l4 * 8);
      short8 pa1 = *(const short8*)(p_s + (wn * 32 + 16 + l15) * 72 + kc * 32 + l4 * 8);
      short8 vb0 = *(const short8*)(smem + 16384 + cur + r0 * 128 + ((cx ^ (r0 & 7)) << 4));
      short8 vb1 = *(const short8*)(smem + 16384 + cur + r1 * 128 + ((cx ^ (r1 & 7)) << 4));
      acc_o[0][0] = MFMA_BF16(pa0, vb0, acc_o[0][0]);
      acc_o[0][1] = MFMA_BF16(pa0, vb1, acc_o[0][1]);
      acc_o[1][0] = MFMA_BF16(pa1, vb0, acc_o[1][0]);
      acc_o[1][1] = MFMA_BF16(pa1, vb1, acc_o[1][1]);
    }
    __builtin_amdgcn_s_setprio(0);
  }
  __syncthreads();
#pragma unroll
  for (int qi = 0; qi < 2; ++qi)
#pragma unroll
    for (int di = 0; di < 2; ++di)
#pragma unroll
      for (int j = 0; j < 4; ++j)
        o_s[(wn * 32 + qi * 16 + l4 * 4 + j) * 68 + wm * 32 + di * 16 + l15] = acc_o[qi][di][j];
  __syncthreads();
  // TanhNorm: out = tanh(n) * out / (n + eps)
  {
    const int row = tid >> 2, q4 = tid & 3;
    float vals[16];
    float ss = 0.f;
#pragma unroll
    for (int j = 0; j < 16; ++j) {
      vals[j] = o_s[row * 68 + q4 * 16 + j];
      ss += vals[j] * vals[j];
    }
    ss += __shfl_xor(ss, 1);
    ss += __shfl_xor(ss, 2);
    const float nrm = sqrtf(ss);
    const float sc = tanhf(nrm) / (nrm + 1e-8f);
    unsigned short* dst = attn + (size_t)(b * 2048 + qbase + row) * 768 + h * 64 + q4 * 16;
    uint4v o0 = {pack2(vals[0] * sc, vals[1] * sc), pack2(vals[2] * sc, vals[3] * sc),
                 pack2(vals[4] * sc, vals[5] * sc), pack2(vals[6] * sc, vals[7] * sc)};
    uint4v o1 = {pack2(vals[8] * sc, vals[9] * sc), pack2(vals[10] * sc, vals[11] * sc),
                 pack2(vals[12] * sc, vals[13] * sc), pack2(vals[14] * sc, vals[15] * sc)};
    *(uint4v*)(dst) = o0;
    *(uint4v*)(dst + 8) = o1;
  }
}

// ---------------------------------------------------------------------------
// Kernel 3: out = attn[4096x768](bf16) @ Wo^T(bf16) -> f32. 128x128 tile,
// DOUBLE-BUFFERED K-loop (round-9 proven). grid = (32, 6); block 256.
// ---------------------------------------------------------------------------
__global__ __launch_bounds__(256) void k_outproj(const unsigned short* __restrict__ attn,
                                                 const unsigned short* __restrict__ Wob,
                                                 float* __restrict__ out) {
  __shared__ alignas(16) unsigned char smem[65536];
  const int mbase = blockIdx.x * 128;
  const int nb = blockIdx.y;
  const int tid = threadIdx.x;
  const int lane = tid & 63;
  const int wv = tid >> 6;
  const int wm = wv >> 1, wn = wv & 1;
  const int l15 = lane & 15, l4 = lane >> 4;
  const int srow8 = lane >> 3;
  const int schunk = (lane & 7) ^ srow8;

  f32x4 acc[4][4];
#pragma unroll
  for (int m = 0; m < 4; ++m)
#pragma unroll
    for (int n = 0; n < 4; ++n) acc[m][n] = (f32x4){0.f, 0.f, 0.f, 0.f};

  // prologue: stage ks=0 into buffer 0
#pragma unroll
  for (int i = 0; i < 4; ++i) {
    const int j = wv * 4 + i;
    gload_lds16(attn + (size_t)(mbase + j * 8 + srow8) * 768 + schunk * 8, smem + j * 1024);
    gload_lds16(Wob + (size_t)(nb * 128 + j * 8 + srow8) * 768 + schunk * 8,
                smem + 16384 + j * 1024);
  }

  for (int ks = 0; ks < 12; ++ks) {
    const int cur = (ks & 1) * 32768;
    asm volatile("s_waitcnt vmcnt(0)" ::: "memory");
    __builtin_amdgcn_sched_barrier(0);
    __builtin_amdgcn_s_barrier();
    __builtin_amdgcn_sched_barrier(0);
    if (ks < 11) {
      const int nxt = ((ks + 1) & 1) * 32768;
      const int k0n = (ks + 1) * 64;
#pragma unroll
      for (int i = 0; i < 4; ++i) {
        const int j = wv * 4 + i;
        gload_lds16(attn + (size_t)(mbase + j * 8 + srow8) * 768 + k0n + schunk * 8,
                    smem + nxt + j * 1024);
        gload_lds16(Wob + (size_t)(nb * 128 + j * 8 + srow8) * 768 + k0n + schunk * 8,
                    smem + nxt + 16384 + j * 1024);
      }
      __builtin_amdgcn_sched_barrier(0);
    }
    __builtin_amdgcn_s_setprio(1);
#pragma unroll
    for (int kc = 0; kc < 2; ++kc) {
      const int cx = (kc << 2) | l4;
      short8 ar[4], br[4];
#pragma unroll
      for (int m = 0; m < 4; ++m) {
        const int r = wm * 64 + m * 16 + l15;
        ar[m] = *(const short8*)(smem + cur + r * 128 + ((cx ^ (r & 7)) << 4));
      }
#pragma unroll
      for (int n = 0; n < 4; ++n) {
        const int r = wn * 64 + n * 16 + l15;
        br[n] = *(const short8*)(smem + cur + 16384 + r * 128 + ((cx ^ (r & 7)) << 4));
      }
#pragma unroll
      for (int m = 0; m < 4; ++m)
#pragma unroll
        for (int n = 0; n < 4; ++n) acc[m][n] = MFMA_BF16(ar[m], br[n], acc[m][n]);
    }
    __builtin_amdgcn_s_setprio(0);
  }
#pragma unroll
  for (int m = 0; m < 4; ++m)
#pragma unroll
    for (int n = 0; n < 4; ++n)
#pragma unroll
      for (int j = 0; j < 4; ++j)
        out[(size_t)(mbase + wm * 64 + m * 16 + l4 * 4 + j) * 768 + nb * 128 + wn * 64 + n * 16 +
            l15] = acc[m][n][j];
}

extern "C" void kernel_launch(void* const* d_in, const int* in_sizes, int n_in, void* d_out,
                              int out_size, void* d_ws, size_t ws_size, hipStream_t stream) {
  (void)in_sizes;
  (void)n_in;
  (void)out_size;
  (void)ws_size;
  const float* query = (const float*)d_in[0];
  const float* key = (const float*)d_in[1];
  const float* value = (const float*)d_in[2];
  const float* Wq = (const float*)d_in[3];
  const float* Wk = (const float*)d_in[4];
  const float* Wv = (const float*)d_in[5];
  const float* Wo = (const float*)d_in[6];
  const float* s_v = (const float*)d_in[7];
  const float* s_r = (const float*)d_in[8];
  float* out = (float*)d_out;

  // ws layout (bf16 elems): [Wb 4x589824 | qb | kb | vtb | attn]  (~29.9 MB)
  unsigned short* Wb = (unsigned short*)d_ws;
  unsigned short* qb = Wb + 2359296;
  unsigned short* kb = qb + 3145728;
  unsigned short* vtb = kb + 3145728;
  unsigned short* attn = vtb + 3145728;

  k_cvtW<<<1152, 256, 0, stream>>>(Wq, Wk, Wv, Wo, Wb);
  k_proj<<<dim3(32, 6, 3), 256, 0, stream>>>(query, key, value, Wb, qb, kb, vtb);
  k_attn<<<dim3(768), 256, 0, stream>>>(qb, kb, vtb, s_v, s_r, attn);
  k_outproj<<<dim3(32, 6), 256, 0, stream>>>(attn, Wb + 3 * 589824, out);
}

// Round 11
// 89.528 us; speedup vs baseline: 1.4919x; 1.4919x over previous
//
#include <hip/hip_runtime.h>
#include <hip/hip_bf16.h>
#include <math.h>

// ScreeningAttention: B=2, T=2048, D_MODEL=768, H=12, D=64
// Round 11 = round-9 artifact (best passing, 90.4us) + k_attn Q read direct
// from global (round-3-proven), Q-LDS stage removed.
// k_cvt (f32->bf16 once) -> k_proj (128x128 MFMA GEMM, dbuf) -> k_attn
// (balanced causal screening attn, dbuf prefetch) -> k_outproj (dbuf GEMM).
// NOTE: v_cvt_pk_bf16_f32 inline-asm packing was a correctness bug (r4/6/7);
// bit-manip RNE is the proven path. A-direct-from-f32 regressed (r10:
// frag-ownership loads are uncoalesced, 3KB lane stride).

typedef __attribute__((ext_vector_type(8))) short short8;     // 8 bf16, MFMA A/B frag
typedef __attribute__((ext_vector_type(4))) float f32x4;      // MFMA C/D frag
typedef __attribute__((ext_vector_type(4))) unsigned int uint4v;
typedef __attribute__((ext_vector_type(2))) unsigned int uint2v;
typedef __attribute__((ext_vector_type(4))) float float4v;

#define MFMA_BF16(a, b, c) __builtin_amdgcn_mfma_f32_16x16x32_bf16((a), (b), (c), 0, 0, 0)

// round-to-nearest-even f32->bf16, bit-manip (round-3-proven).
static __device__ __forceinline__ unsigned short f2bf(float f) {
  union { float f; unsigned u; } v; v.f = f;
  unsigned r = v.u + 0x7FFFu + ((v.u >> 16) & 1u);
  return (unsigned short)(r >> 16);
}
static __device__ __forceinline__ unsigned pack2(float a, float b) {
  return (unsigned)f2bf(a) | ((unsigned)f2bf(b) << 16);
}
// async global->LDS, 16B per lane. LDS dest = wave-uniform base + lane*16.
static __device__ __forceinline__ void gload_lds16(const void* g, void* l) {
  __builtin_amdgcn_global_load_lds((const __attribute__((address_space(1))) unsigned int*)g,
                                   (__attribute__((address_space(3))) unsigned int*)l, 16, 0, 0);
}

// ---------------------------------------------------------------------------
// Kernel 0: convert Xq,Xk,Xv (3x3145728) + Wq,Wk,Wv,Wo (4x589824) f32->bf16
// into one contiguous bf16 region. grid 5760x256, 8 elems/thread.
// ---------------------------------------------------------------------------
__global__ __launch_bounds__(256) void k_cvt(
    const float* __restrict__ s0, const float* __restrict__ s1, const float* __restrict__ s2,
    const float* __restrict__ s3, const float* __restrict__ s4, const float* __restrict__ s5,
    const float* __restrict__ s6, unsigned short* __restrict__ dst) {
  const size_t e = ((size_t)blockIdx.x * 256 + threadIdx.x) * 8;
  const float* src;
  size_t off;
  if (e < 9437184) {
    const int i = (int)(e / 3145728);
    src = (i == 0) ? s0 : (i == 1) ? s1 : s2;
    off = e - (size_t)i * 3145728;
  } else {
    const size_t ew = e - 9437184;
    const int i = (int)(ew / 589824);
    src = (i == 0) ? s3 : (i == 1) ? s4 : (i == 2) ? s5 : s6;
    off = ew - (size_t)i * 589824;
  }
  const float4v f0 = *(const float4v*)(src + off);
  const float4v f1 = *(const float4v*)(src + off + 4);
  uint4v u = {pack2(f0.x, f0.y), pack2(f0.z, f0.w), pack2(f1.x, f1.y), pack2(f1.z, f1.w)};
  *(uint4v*)(dst + e) = u;
}

// ---------------------------------------------------------------------------
// Kernel 1: QKV projection (bf16 inputs) + per-head l2 normalization.
// 128x128 tile, BK=64, 4 waves (2x2, 64x64 each, 4x4 frags).
// K-loop DOUBLE-BUFFERED (A0/B0 @0/16K, A1/B1 @32K/48K): per iter
// {vmcnt(0)+barrier -> prefetch ks+1 -> MFMA from cur}. One barrier/k-step.
// LDS tiles linear with XOR chunk-swizzle (chunk ^= row&7) on both sides.
// which==2 (V) writes TRANSPOSED to vtb [bh][d][t].
// grid = (32, 6, 3); block = 256.
// ---------------------------------------------------------------------------
__global__ __launch_bounds__(256) void k_proj(
    const unsigned short* __restrict__ Xb, const unsigned short* __restrict__ Wb,
    unsigned short* __restrict__ qb, unsigned short* __restrict__ kb,
    unsigned short* __restrict__ vtb) {
  __shared__ alignas(16) unsigned char smem[65536];
  float* o_s = (float*)smem;               // f32[128][68] epilogue alias (34816 B)
  unsigned short* vt_s = (unsigned short*)smem;  // bf16[64][136] V epilogue alias

  const int which = blockIdx.z;
  const unsigned short* X = Xb + (size_t)which * 3145728;
  const unsigned short* W = Wb + (size_t)which * 589824;

  const int mbase = blockIdx.x * 128;
  const int nb = blockIdx.y;  // 2 heads per block
  const int tid = threadIdx.x;
  const int lane = tid & 63;
  const int wv = tid >> 6;
  const int wm = wv >> 1, wn = wv & 1;
  const int l15 = lane & 15, l4 = lane >> 4;

  const int srow8 = lane >> 3;
  const int schunk = (lane & 7) ^ srow8;

  f32x4 acc[4][4];
#pragma unroll
  for (int m = 0; m < 4; ++m)
#pragma unroll
    for (int n = 0; n < 4; ++n) acc[m][n] = (f32x4){0.f, 0.f, 0.f, 0.f};

  // prologue: stage ks=0 into buffer 0 (loop-top vmcnt+barrier covers the wait)
#pragma unroll
  for (int i = 0; i < 4; ++i) {
    const int j = wv * 4 + i;
    gload_lds16(X + (size_t)(mbase + j * 8 + srow8) * 768 + schunk * 8, smem + j * 1024);
    gload_lds16(W + (size_t)(nb * 128 + j * 8 + srow8) * 768 + schunk * 8,
                smem + 16384 + j * 1024);
  }

  for (int ks = 0; ks < 12; ++ks) {
    const int cur = (ks & 1) * 32768;
    // my prefetch done -> barrier -> everyone's prefetch done
    asm volatile("s_waitcnt vmcnt(0)" ::: "memory");
    __builtin_amdgcn_sched_barrier(0);
    __builtin_amdgcn_s_barrier();
    __builtin_amdgcn_sched_barrier(0);
    if (ks < 11) {
      const int nxt = ((ks + 1) & 1) * 32768;
      const int k0n = (ks + 1) * 64;
#pragma unroll
      for (int i = 0; i < 4; ++i) {
        const int j = wv * 4 + i;
        gload_lds16(X + (size_t)(mbase + j * 8 + srow8) * 768 + k0n + schunk * 8,
                    smem + nxt + j * 1024);
        gload_lds16(W + (size_t)(nb * 128 + j * 8 + srow8) * 768 + k0n + schunk * 8,
                    smem + nxt + 16384 + j * 1024);
      }
      __builtin_amdgcn_sched_barrier(0);  // pin prefetch issue before compute
    }
    __builtin_amdgcn_s_setprio(1);
#pragma unroll
    for (int kc = 0; kc < 2; ++kc) {
      const int cx = (kc << 2) | l4;
      short8 ar[4], br[4];
#pragma unroll
      for (int m = 0; m < 4; ++m) {
        const int r = wm * 64 + m * 16 + l15;
        ar[m] = *(const short8*)(smem + cur + r * 128 + ((cx ^ (r & 7)) << 4));
      }
#pragma unroll
      for (int n = 0; n < 4; ++n) {
        const int r = wn * 64 + n * 16 + l15;
        br[n] = *(const short8*)(smem + cur + 16384 + r * 128 + ((cx ^ (r & 7)) << 4));
      }
#pragma unroll
      for (int m = 0; m < 4; ++m)
#pragma unroll
        for (int n = 0; n < 4; ++n) acc[m][n] = MFMA_BF16(ar[m], br[n], acc[m][n]);
    }
    __builtin_amdgcn_s_setprio(0);
  }

  // epilogue: per col-half pass p (head h = nb*2+p)
  const int b = mbase >> 11;
  const int tbase = mbase & 2047;
  const int row2 = tid >> 1, half = tid & 1;
  for (int p = 0; p < 2; ++p) {
    __syncthreads();
    if (wn == p) {
#pragma unroll
      for (int m = 0; m < 4; ++m)
#pragma unroll
        for (int n = 0; n < 4; ++n)
#pragma unroll
          for (int j = 0; j < 4; ++j)
            o_s[(wm * 64 + m * 16 + l4 * 4 + j) * 68 + n * 16 + l15] = acc[m][n][j];
    }
    __syncthreads();
    float v[32];
    float ss = 0.f;
#pragma unroll
    for (int c = 0; c < 8; ++c) {
      float4v f = *(const float4v*)(o_s + row2 * 68 + half * 32 + c * 4);
      v[c * 4 + 0] = f.x; v[c * 4 + 1] = f.y; v[c * 4 + 2] = f.z; v[c * 4 + 3] = f.w;
      ss += f.x * f.x + f.y * f.y + f.z * f.z + f.w * f.w;
    }
    ss += __shfl_xor(ss, 1);
    const float inv = 1.f / fmaxf(sqrtf(ss), 1e-8f);
    const int h = nb * 2 + p, bh = b * 12 + h;
    if (which < 2) {
      unsigned short* outp =
          ((which == 0) ? qb : kb) + ((size_t)bh * 2048 + tbase + row2) * 64 + half * 32;
#pragma unroll
      for (int c = 0; c < 4; ++c) {
        uint4v o = {pack2(v[c * 8 + 0] * inv, v[c * 8 + 1] * inv),
                    pack2(v[c * 8 + 2] * inv, v[c * 8 + 3] * inv),
                    pack2(v[c * 8 + 4] * inv, v[c * 8 + 5] * inv),
                    pack2(v[c * 8 + 6] * inv, v[c * 8 + 7] * inv)};
        *(uint4v*)(outp + c * 8) = o;
      }
      __syncthreads();
    } else {
      __syncthreads();  // o_s reads done; vt_s aliases o_s
#pragma unroll
      for (int c = 0; c < 32; ++c)
        vt_s[(half * 32 + c) * 136 + row2] = f2bf(v[c] * inv);
      __syncthreads();
      const int d = tid >> 2, tc = (tid & 3) * 32;
      unsigned short* dst = vtb + ((size_t)bh * 64 + d) * 2048 + tbase + tc;
#pragma unroll
      for (int c = 0; c < 4; ++c)
        *(uint4v*)(dst + c * 8) = *(const uint4v*)(vt_s + d * 136 + tc + c * 8);
      __syncthreads();
    }
  }
}

// ---------------------------------------------------------------------------
// Kernel 2: causal screening attention. Swapped-S MFMA (reg-dim = keys),
// Q fragments read DIRECTLY from global (round-3-proven; no Q LDS stage),
// K/V^T DOUBLE-BUFFERED via global_load_lds; full vmcnt(0) drains only.
// Balanced flat grid (heavy+light task pairing).
// LDS: K0 @0, K1 @8192, V0 @16384, V1 @24576, p_s @32768 (9216). 41984 B.
// block = 256 (4 waves, 2x2).
// ---------------------------------------------------------------------------
__global__ __launch_bounds__(256) void k_attn(
    const unsigned short* __restrict__ qb, const unsigned short* __restrict__ kb,
    const unsigned short* __restrict__ vtb, const float* __restrict__ s_v,
    const float* __restrict__ s_r, unsigned short* __restrict__ attn) {
  __shared__ alignas(16) unsigned char smem[41984];
  unsigned short* p_s = (unsigned short*)(smem + 32768);  // [64 q][72 key] bf16
  float* o_s = (float*)smem;                              // [64][68] f32 epilogue alias

  const int bid = blockIdx.x;
  const int ii = bid & 255, jj = bid >> 8;
  const int rank = (jj == 0) ? ii : (jj == 1) ? (511 - ii) : (512 + ii);
  const int qt = 31 - (rank / 24);  // heavy tasks at low rank
  const int bh = rank % 24;
  const int b = bh / 12, h = bh % 12;
  const int qbase = qt * 64;
  const unsigned short* Qp = qb + (size_t)bh * 2048 * 64;
  const unsigned short* Kp = kb + (size_t)bh * 2048 * 64;
  const unsigned short* VTp = vtb + (size_t)bh * 64 * 2048;

  const int tid = threadIdx.x;
  const int lane = tid & 63;
  const int wv = tid >> 6;
  const int wm = wv >> 1, wn = wv & 1;  // S: wm=keys, wn=q. PV: wm=d, wn=q.
  const int l15 = lane & 15, l4 = lane >> 4;
  const int srow8 = lane >> 3;
  const int schunk = (lane & 7) ^ srow8;

  const float w_h = expf(s_v[h]) + 1.0f;          // decay exponent, [2,256]
  const float lr_h = log2f(expf(s_r[h]) + 1.0f);  // log2 of per-head scale

  // prologue: issue kt=0 K/V gloads (loop-top vmcnt(0)+barrier covers them)
#pragma unroll
  for (int i = 0; i < 2; ++i) {
    const int j = wv * 2 + i;
    gload_lds16(Kp + (size_t)(j * 8 + srow8) * 64 + schunk * 8, smem + j * 1024);
    gload_lds16(VTp + (size_t)(j * 8 + srow8) * 2048 + schunk * 8, smem + 16384 + j * 1024);
  }

  // hoist Q fragments (B-operand of swapped S) straight from global (r3-proven)
  short8 qf[2][2];
#pragma unroll
  for (int n = 0; n < 2; ++n)
#pragma unroll
    for (int kc = 0; kc < 2; ++kc)
      qf[n][kc] = *(const short8*)(Qp + (size_t)(qbase + wn * 32 + n * 16 + l15) * 64 + kc * 32 +
                                   l4 * 8);

  f32x4 acc_o[2][2];  // [qi][di]
#pragma unroll
  for (int m = 0; m < 2; ++m)
#pragma unroll
    for (int n = 0; n < 2; ++n) acc_o[m][n] = (f32x4){0.f, 0.f, 0.f, 0.f};

  for (int kt = 0; kt <= qt; ++kt) {
    const int cur = (kt & 1) * 8192;
    // wait current tile's K/V (the only outstanding VMEM = prev prefetch), sync
    asm volatile("s_waitcnt vmcnt(0)" ::: "memory");
    __builtin_amdgcn_sched_barrier(0);
    __builtin_amdgcn_s_barrier();
    __builtin_amdgcn_sched_barrier(0);
    // prefetch kt+1 into the other buffer (all waves past kt-1 reads now)
    if (kt < qt) {
      const int nxt = ((kt + 1) & 1) * 8192;
      const int kb2 = (kt + 1) * 64;
#pragma unroll
      for (int i = 0; i < 2; ++i) {
        const int j = wv * 2 + i;
        gload_lds16(Kp + (size_t)(kb2 + j * 8 + srow8) * 64 + schunk * 8, smem + nxt + j * 1024);
        gload_lds16(VTp + (size_t)(j * 8 + srow8) * 2048 + kb2 + schunk * 8,
                    smem + 16384 + nxt + j * 1024);
      }
      __builtin_amdgcn_sched_barrier(0);  // pin prefetch issue before compute
    }
    // S^T = K Q^T : rows = keys, cols = q
    f32x4 s_acc[2][2];
#pragma unroll
    for (int m = 0; m < 2; ++m)
#pragma unroll
      for (int n = 0; n < 2; ++n) s_acc[m][n] = (f32x4){0.f, 0.f, 0.f, 0.f};
    __builtin_amdgcn_s_setprio(1);
#pragma unroll
    for (int kc = 0; kc < 2; ++kc) {
      const int cx = (kc << 2) | l4;
      const int r0 = wm * 32 + l15, r1 = wm * 32 + 16 + l15;
      short8 a0 = *(const short8*)(smem + cur + r0 * 128 + ((cx ^ (r0 & 7)) << 4));
      short8 a1 = *(const short8*)(smem + cur + r1 * 128 + ((cx ^ (r1 & 7)) << 4));
      s_acc[0][0] = MFMA_BF16(a0, qf[0][kc], s_acc[0][0]);
      s_acc[0][1] = MFMA_BF16(a0, qf[1][kc], s_acc[0][1]);
      s_acc[1][0] = MFMA_BF16(a1, qf[0][kc], s_acc[1][0]);
      s_acc[1][1] = MFMA_BF16(a1, qf[1][kc], s_acc[1][1]);
    }
    __builtin_amdgcn_s_setprio(0);
    // alpha = r * clamp((s+1)/2)^w ; frag reg-dim = consecutive keys -> b64 stores
    const bool diag = (kt == qt);
#pragma unroll
    for (int m = 0; m < 2; ++m)
#pragma unroll
      for (int n = 0; n < 2; ++n) {
        const int lkb = wm * 32 + m * 16 + l4 * 4;  // key base (reg dim)
        const int lq = wn * 32 + n * 16 + l15;      // q (lane dim)
        float av[4];
#pragma unroll
        for (int t = 0; t < 4; ++t) {
          const float base = __builtin_amdgcn_fmed3f(fmaf(s_acc[m][n][t], 0.5f, 0.5f), 0.f, 1.f);
          float a = __builtin_amdgcn_exp2f(fmaf(w_h, __builtin_amdgcn_logf(base), lr_h));
          if (diag && (lkb + t) > lq) a = 0.f;
          av[t] = a;
        }
        uint2v u = {pack2(av[0], av[1]), pack2(av[2], av[3])};
        *(uint2v*)(p_s + lq * 72 + lkb) = u;
      }
    // drain LDS writes of P, then sync (raw barrier: keep prefetch in flight)
    asm volatile("s_waitcnt lgkmcnt(0)" ::: "memory");
    __builtin_amdgcn_sched_barrier(0);
    __builtin_amdgcn_s_barrier();
    __builtin_amdgcn_sched_barrier(0);
    // O += P V : A = P[q][key] (padded b128 rows), B = V^T[d][key] (swizzled)
    __builtin_amdgcn_s_setprio(1);
#pragma unroll
    for (int kc = 0; kc < 2; ++kc) {
      const int cx = (kc << 2) | l4;
      const int r0 = wm * 32 + l15, r1 = wm * 32 + 16 + l15;
      short8 pa0 = *(const short8*)(p_s + (wn * 32 + l15) * 72 + kc * 32 + l4 * 8);
      short8 pa1 = *(const short8*)(p_s + (wn * 32 + 16 + l15) * 72 + kc * 32 + l4 * 8);
      short8 vb0 = *(const short8*)(smem + 16384 + cur + r0 * 128 + ((cx ^ (r0 & 7)) << 4));
      short8 vb1 = *(const short8*)(smem + 16384 + cur + r1 * 128 + ((cx ^ (r1 & 7)) << 4));
      acc_o[0][0] = MFMA_BF16(pa0, vb0, acc_o[0][0]);
      acc_o[0][1] = MFMA_BF16(pa0, vb1, acc_o[0][1]);
      acc_o[1][0] = MFMA_BF16(pa1, vb0, acc_o[1][0]);
      acc_o[1][1] = MFMA_BF16(pa1, vb1, acc_o[1][1]);
    }
    __builtin_amdgcn_s_setprio(0);
  }
  __syncthreads();
#pragma unroll
  for (int qi = 0; qi < 2; ++qi)
#pragma unroll
    for (int di = 0; di < 2; ++di)
#pragma unroll
      for (int j = 0; j < 4; ++j)
        o_s[(wn * 32 + qi * 16 + l4 * 4 + j) * 68 + wm * 32 + di * 16 + l15] = acc_o[qi][di][j];
  __syncthreads();
  // TanhNorm: out = tanh(n) * out / (n + eps)
  {
    const int row = tid >> 2, q4 = tid & 3;
    float vals[16];
    float ss = 0.f;
#pragma unroll
    for (int j = 0; j < 16; ++j) {
      vals[j] = o_s[row * 68 + q4 * 16 + j];
      ss += vals[j] * vals[j];
    }
    ss += __shfl_xor(ss, 1);
    ss += __shfl_xor(ss, 2);
    const float nrm = sqrtf(ss);
    const float sc = tanhf(nrm) / (nrm + 1e-8f);
    unsigned short* dst = attn + (size_t)(b * 2048 + qbase + row) * 768 + h * 64 + q4 * 16;
    uint4v o0 = {pack2(vals[0] * sc, vals[1] * sc), pack2(vals[2] * sc, vals[3] * sc),
                 pack2(vals[4] * sc, vals[5] * sc), pack2(vals[6] * sc, vals[7] * sc)};
    uint4v o1 = {pack2(vals[8] * sc, vals[9] * sc), pack2(vals[10] * sc, vals[11] * sc),
                 pack2(vals[12] * sc, vals[13] * sc), pack2(vals[14] * sc, vals[15] * sc)};
    *(uint4v*)(dst) = o0;
    *(uint4v*)(dst + 8) = o1;
  }
}

// ---------------------------------------------------------------------------
// Kernel 3: out = attn[4096x768](bf16) @ Wo^T(bf16) -> f32. 128x128 tile,
// DOUBLE-BUFFERED K-loop (round-9 proven). grid = (32, 6); block 256.
// ---------------------------------------------------------------------------
__global__ __launch_bounds__(256) void k_outproj(const unsigned short* __restrict__ attn,
                                                 const unsigned short* __restrict__ Wob,
                                                 float* __restrict__ out) {
  __shared__ alignas(16) unsigned char smem[65536];
  const int mbase = blockIdx.x * 128;
  const int nb = blockIdx.y;
  const int tid = threadIdx.x;
  const int lane = tid & 63;
  const int wv = tid >> 6;
  const int wm = wv >> 1, wn = wv & 1;
  const int l15 = lane & 15, l4 = lane >> 4;
  const int srow8 = lane >> 3;
  const int schunk = (lane & 7) ^ srow8;

  f32x4 acc[4][4];
#pragma unroll
  for (int m = 0; m < 4; ++m)
#pragma unroll
    for (int n = 0; n < 4; ++n) acc[m][n] = (f32x4){0.f, 0.f, 0.f, 0.f};

  // prologue: stage ks=0 into buffer 0
#pragma unroll
  for (int i = 0; i < 4; ++i) {
    const int j = wv * 4 + i;
    gload_lds16(attn + (size_t)(mbase + j * 8 + srow8) * 768 + schunk * 8, smem + j * 1024);
    gload_lds16(Wob + (size_t)(nb * 128 + j * 8 + srow8) * 768 + schunk * 8,
                smem + 16384 + j * 1024);
  }

  for (int ks = 0; ks < 12; ++ks) {
    const int cur = (ks & 1) * 32768;
    asm volatile("s_waitcnt vmcnt(0)" ::: "memory");
    __builtin_amdgcn_sched_barrier(0);
    __builtin_amdgcn_s_barrier();
    __builtin_amdgcn_sched_barrier(0);
    if (ks < 11) {
      const int nxt = ((ks + 1) & 1) * 32768;
      const int k0n = (ks + 1) * 64;
#pragma unroll
      for (int i = 0; i < 4; ++i) {
        const int j = wv * 4 + i;
        gload_lds16(attn + (size_t)(mbase + j * 8 + srow8) * 768 + k0n + schunk * 8,
                    smem + nxt + j * 1024);
        gload_lds16(Wob + (size_t)(nb * 128 + j * 8 + srow8) * 768 + k0n + schunk * 8,
                    smem + nxt + 16384 + j * 1024);
      }
      __builtin_amdgcn_sched_barrier(0);
    }
    __builtin_amdgcn_s_setprio(1);
#pragma unroll
    for (int kc = 0; kc < 2; ++kc) {
      const int cx = (kc << 2) | l4;
      short8 ar[4], br[4];
#pragma unroll
      for (int m = 0; m < 4; ++m) {
        const int r = wm * 64 + m * 16 + l15;
        ar[m] = *(const short8*)(smem + cur + r * 128 + ((cx ^ (r & 7)) << 4));
      }
#pragma unroll
      for (int n = 0; n < 4; ++n) {
        const int r = wn * 64 + n * 16 + l15;
        br[n] = *(const short8*)(smem + cur + 16384 + r * 128 + ((cx ^ (r & 7)) << 4));
      }
#pragma unroll
      for (int m = 0; m < 4; ++m)
#pragma unroll
        for (int n = 0; n < 4; ++n) acc[m][n] = MFMA_BF16(ar[m], br[n], acc[m][n]);
    }
    __builtin_amdgcn_s_setprio(0);
  }
#pragma unroll
  for (int m = 0; m < 4; ++m)
#pragma unroll
    for (int n = 0; n < 4; ++n)
#pragma unroll
      for (int j = 0; j < 4; ++j)
        out[(size_t)(mbase + wm * 64 + m * 16 + l4 * 4 + j) * 768 + nb * 128 + wn * 64 + n * 16 +
            l15] = acc[m][n][j];
}

extern "C" void kernel_launch(void* const* d_in, const int* in_sizes, int n_in, void* d_out,
                              int out_size, void* d_ws, size_t ws_size, hipStream_t stream) {
  (void)in_sizes;
  (void)n_in;
  (void)out_size;
  (void)ws_size;
  const float* query = (const float*)d_in[0];
  const float* key = (const float*)d_in[1];
  const float* value = (const float*)d_in[2];
  const float* Wq = (const float*)d_in[3];
  const float* Wk = (const float*)d_in[4];
  const float* Wv = (const float*)d_in[5];
  const float* Wo = (const float*)d_in[6];
  const float* s_v = (const float*)d_in[7];
  const float* s_r = (const float*)d_in[8];
  float* out = (float*)d_out;

  // ws layout (bf16 elems): [Xb 3x3145728 | Wb 4x589824 | qb | kb | vtb]
  // attn aliases Xb (dead after k_proj). Total 42.5 MB.
  unsigned short* cvt = (unsigned short*)d_ws;
  unsigned short* Xb = cvt;
  unsigned short* Wb = cvt + 9437184;
  unsigned short* qb = cvt + 11796480;
  unsigned short* kb = qb + 3145728;
  unsigned short* vtb = kb + 3145728;
  unsigned short* attn = cvt;

  k_cvt<<<5760, 256, 0, stream>>>(query, key, value, Wq, Wk, Wv, Wo, cvt);
  k_proj<<<dim3(32, 6, 3), 256, 0, stream>>>(Xb, Wb, qb, kb, vtb);
  k_attn<<<dim3(768), 256, 0, stream>>>(qb, kb, vtb, s_v, s_r, attn);
  k_outproj<<<dim3(32, 6), 256, 0, stream>>>(attn, Wb + 3 * 589824, out);
}